// Round 9
// baseline (312.953 us; speedup 1.0000x reference)
//
#include <hip/hip_runtime.h>
#include <hip/hip_bf16.h>
#include <math.h>

#define N_TOK 8192
#define DIM   1024
#define E_R   32
#define H_E   128
#define HS    512
#define TOPK  4
#define RKS   8            // router K-splits
#define RKL   (DIM / RKS)  // 128 K per split
#define MAXSLOT 34816

typedef __bf16 bf16;
typedef __bf16 bf16x8 __attribute__((ext_vector_type(8)));
typedef float  floatx4 __attribute__((ext_vector_type(4)));

#define MFMA16(a,b,c) __builtin_amdgcn_mfma_f32_16x16x32_bf16(a,b,c,0,0,0)

__device__ __forceinline__ void gl_lds16(const bf16* g, bf16* l) {
    __builtin_amdgcn_global_load_lds(
        (const __attribute__((address_space(1))) void*)g,
        (__attribute__((address_space(3))) void*)l, 16, 0, 0);
}

// XCD-chunked bijective swizzle (m204): each XCD owns a contiguous logical
// block range -> blocks sharing weight panels hit the same L2. (R8: -32% FETCH)
__device__ __forceinline__ int xcd_swz(int b, int n) {
    int q = n >> 3, r = n & 7;
    int xcd = b & 7, idx = b >> 3;
    return (xcd < r ? xcd * (q + 1) : r * (q + 1) + (xcd - r) * q) + idx;
}

// ---------------------------------------------------------------- fused convert
__global__ __launch_bounds__(256)
void cvt_all(const float* __restrict__ x, const float* __restrict__ g,
             const float* __restrict__ u, const float* __restrict__ d,
             const float* __restrict__ sg, const float* __restrict__ su,
             const float* __restrict__ sd,
             bf16* __restrict__ xb, bf16* __restrict__ gb, bf16* __restrict__ ub,
             bf16* __restrict__ db, bf16* __restrict__ sgb, bf16* __restrict__ sub,
             bf16* __restrict__ sdb) {
    int b = blockIdx.x;
    const float* s; bf16* o; int lb;
    if      (b < 4096)  { s = x;  o = xb;  lb = b; }
    else if (b < 6144)  { s = g;  o = gb;  lb = b - 4096; }
    else if (b < 8192)  { s = u;  o = ub;  lb = b - 6144; }
    else if (b < 10240) { s = d;  o = db;  lb = b - 8192; }
    else if (b < 10496) { s = sg; o = sgb; lb = b - 10240; }
    else if (b < 10752) { s = su; o = sub; lb = b - 10496; }
    else                { s = sd; o = sdb; lb = b - 10752; }
    size_t i = (size_t)lb * 2048 + threadIdx.x * 8;
    float4 v0 = *(const float4*)(s + i);
    float4 v1 = *(const float4*)(s + i + 4);
    bf16x8 r = {(bf16)v0.x,(bf16)v0.y,(bf16)v0.z,(bf16)v0.w,
                (bf16)v1.x,(bf16)v1.y,(bf16)v1.z,(bf16)v1.w};
    *(bf16x8*)(o + i) = r;
}

// ---------------------------------------------------------------- router v4: LDS-staged K-split GEMM
__global__ __launch_bounds__(256)
void router_gemm(const float* __restrict__ x, const float* __restrict__ rw,
                 float* __restrict__ partial) {
    __shared__ float Xs[64 * 132];
    __shared__ float Wt[128 * 32];
    int tid = threadIdx.x;
    int t0  = blockIdx.x * 64;
    int kb  = blockIdx.y * RKL;

#pragma unroll
    for (int j = 0; j < 8; ++j) {
        int flat = j * 1024 + tid * 4;
        int row = flat >> 7, col = flat & 127;
        float4 v = *(const float4*)(x + (size_t)(t0 + row) * DIM + kb + col);
        *(float4*)(&Xs[row * 132 + col]) = v;
    }
    {
        int e = tid >> 3, kq = (tid & 7) * 16;
        const float* wp = rw + (size_t)e * DIM + kb + kq;
#pragma unroll
        for (int i = 0; i < 16; i += 4) {
            float4 v = *(const float4*)(wp + i);
            Wt[(kq + i + 0) * 32 + e] = v.x;
            Wt[(kq + i + 1) * 32 + e] = v.y;
            Wt[(kq + i + 2) * 32 + e] = v.z;
            Wt[(kq + i + 3) * 32 + e] = v.w;
        }
    }
    __syncthreads();

    int eg = tid & 7, tg = tid >> 3;
    float acc[2][4] = {{0.f}};
#pragma unroll 4
    for (int k = 0; k < RKL; k += 4) {
        float4 xa0 = *(const float4*)(&Xs[(tg * 2 + 0) * 132 + k]);
        float4 xa1 = *(const float4*)(&Xs[(tg * 2 + 1) * 132 + k]);
#pragma unroll
        for (int kk = 0; kk < 4; ++kk) {
            float4 w = *(const float4*)(&Wt[(k + kk) * 32 + eg * 4]);
            float x0 = (&xa0.x)[kk], x1 = (&xa1.x)[kk];
            acc[0][0] += x0 * w.x; acc[0][1] += x0 * w.y;
            acc[0][2] += x0 * w.z; acc[0][3] += x0 * w.w;
            acc[1][0] += x1 * w.x; acc[1][1] += x1 * w.y;
            acc[1][2] += x1 * w.z; acc[1][3] += x1 * w.w;
        }
    }
#pragma unroll
    for (int t = 0; t < 2; ++t) {
        floatx4 v = { acc[t][0], acc[t][1], acc[t][2], acc[t][3] };
        *(floatx4*)(&partial[((size_t)blockIdx.y * N_TOK + t0 + tg * 2 + t) * 32 + eg * 4]) = v;
    }
}

// ---------------------------------------------------------------- router finalize
__global__ __launch_bounds__(256)
void router_fin(const float* __restrict__ partial, const float* __restrict__ rb,
                int* __restrict__ counts, int* __restrict__ tlist,
                float* __restrict__ slist, int* __restrict__ tok2slot) {
    __shared__ int lcnt[E_R];
    __shared__ int gbase[E_R];
    int tid = threadIdx.x;
    int n = blockIdx.x * 256 + tid;
    if (tid < E_R) lcnt[tid] = 0;
    __syncthreads();

    float lg[E_R];
#pragma unroll
    for (int e4 = 0; e4 < E_R; e4 += 4) {
        floatx4 s = {0.f, 0.f, 0.f, 0.f};
#pragma unroll
        for (int ks = 0; ks < RKS; ++ks)
            s += *(const floatx4*)(&partial[((size_t)ks * N_TOK + n) * 32 + e4]);
        lg[e4 + 0] = s[0] + rb[e4 + 0];
        lg[e4 + 1] = s[1] + rb[e4 + 1];
        lg[e4 + 2] = s[2] + rb[e4 + 2];
        lg[e4 + 3] = s[3] + rb[e4 + 3];
    }
    float mx = -1e30f;
#pragma unroll
    for (int e = 0; e < E_R; ++e) mx = fmaxf(mx, lg[e]);
    float se = 0.f;
#pragma unroll
    for (int e = 0; e < E_R; ++e) { float v = __expf(lg[e] - mx); lg[e] = v; se += v; }
    float inv = 1.f / se;

    unsigned usedMask = 0;
    int idx[TOPK]; float pv[TOPK]; int lpos[TOPK]; float psum = 0.f;
    for (int k = 0; k < TOPK; ++k) {
        float best = -1.f; int bi = 0;
        for (int e = 0; e < E_R; ++e)
            if (!((usedMask >> e) & 1) && lg[e] > best) { best = lg[e]; bi = e; }
        usedMask |= 1u << bi;
        idx[k] = bi; pv[k] = best * inv; psum += pv[k];
    }
    float norm = 1.f / fmaxf(psum, 1e-12f);
#pragma unroll
    for (int k = 0; k < TOPK; ++k)
        lpos[k] = atomicAdd(&lcnt[idx[k]], 1);
    __syncthreads();
    if (tid < E_R) gbase[tid] = atomicAdd(&counts[tid], lcnt[tid]);
    __syncthreads();
#pragma unroll
    for (int k = 0; k < TOPK; ++k) {
        int e = idx[k];
        int pos = gbase[e] + lpos[k];
        tlist[(size_t)e * N_TOK + pos] = n;
        slist[(size_t)e * N_TOK + pos] = pv[k] * norm;
        tok2slot[(size_t)n * 4 + k] = (e << 16) | pos;
    }
}

// ---------------------------------------------------------------- work-queue build
__global__ void wq_build(const int* __restrict__ counts, int* __restrict__ items,
                         int* __restrict__ nitems, int* __restrict__ expbase) {
    if (threadIdx.x == 0) {
        int n = 0, base = 0;
        for (int e = 0; e < E_R; ++e) {
            int c = counts[e];
            expbase[e] = base;
            int nt = (c + 63) >> 6;
            for (int t = 0; t < nt; ++t)
                items[n++] = (e << 24) | (t << 16) | (base + t * 64);
            base += nt * 64;
        }
        *nitems = n;
    }
}

// ---------------------------------------------------------------- phase 1 FUSED
// Routed blocks: gate/up (BK=64 dbuf, R8-best) -> H tile to LDS (reused As)
// -> down-projection (8 n-chunks of 128, dbuf in Bs halves) -> Od.
// Shared blocks: unchanged (write Hs). LDS stays 80KB -> 2 blocks/CU.
__global__ __launch_bounds__(256, 2)
void phase1(const bf16* __restrict__ xb, const bf16* __restrict__ wg,
            const bf16* __restrict__ wu, const bf16* __restrict__ sg,
            const bf16* __restrict__ su, const bf16* __restrict__ wd,
            const int* __restrict__ counts, const int* __restrict__ tlist,
            const float* __restrict__ slist, const int* __restrict__ items,
            const int* __restrict__ nitems,
            bf16* __restrict__ Hs, bf16* __restrict__ Od) {
    __shared__ __align__(16) bf16 As[2 * 64 * 64];     // 16KB; later: H tile [64][128]
    __shared__ __align__(16) bf16 Bs[2 * 256 * 64];    // 64KB; later: down-B halves [128][128]

    int b = xcd_swz(blockIdx.x, 1056);
    const bf16 *gptr, *uptr;
    bf16* hout = nullptr;
    int e, lbase, cnt = 0, rowbase = 0;
    if (b < 512) {
        int c = b >> 7, t = b & 127;
        gptr = sg + (size_t)c * H_E * DIM;
        uptr = su + (size_t)c * H_E * DIM;
        hout = Hs + (size_t)t * 64 * HS + c * H_E;
        lbase = t * 64;
        e = -1;
    } else {
        int rbk = b - 512;
        if (rbk >= *nitems) return;
        int it = items[rbk];
        e = it >> 24; int t = (it >> 16) & 0xff; rowbase = it & 0xffff;
        gptr = wg + (size_t)e * H_E * DIM;
        uptr = wu + (size_t)e * H_E * DIM;
        cnt = counts[e];
        lbase = t * 64;
    }

    int tid = threadIdx.x;
    int rs = tid >> 3;                               // staging row in 32-row group
    int cOff = ((tid & 7) ^ (rs & 7)) * 8;           // pre-swizzled global chunk
    int tokA, tokB;
    if (e < 0) { tokA = lbase + rs; tokB = lbase + rs + 32; }
    else {
        int liA = lbase + rs;      if (liA >= cnt) liA = cnt - 1;
        int liB = lbase + rs + 32; if (liB >= cnt) liB = cnt - 1;
        tokA = tlist[(size_t)e * N_TOK + liA];
        tokB = tlist[(size_t)e * N_TOK + liB];
    }
    const bf16* aSrc0 = xb + (size_t)tokA * DIM + cOff;
    const bf16* aSrc1 = xb + (size_t)tokB * DIM + cOff;
    const bf16* gSrc  = gptr + (size_t)rs * DIM + cOff;
    const bf16* uSrc  = uptr + (size_t)rs * DIM + cOff;

    int w = tid >> 6, lane = tid & 63, m = lane & 15, quad = lane >> 4;
    int mx7 = m & 7;

    floatx4 aG[4][2] = {{{0}}};
    floatx4 aU[4][2] = {{{0}}};

    #define P1_STAGE(buf, k0)                                                  \
        do {                                                                   \
            bf16* aD = As + (buf) * 4096 + tid * 8;                            \
            bf16* bD = Bs + (buf) * 16384 + tid * 8;                           \
            gl_lds16(aSrc0 + (k0), aD);                                        \
            gl_lds16(aSrc1 + (k0), aD + 2048);                                 \
            gl_lds16(gSrc + (k0),            bD);                              \
            gl_lds16(gSrc + 32 * DIM + (k0), bD + 2048);                       \
            gl_lds16(gSrc + 64 * DIM + (k0), bD + 4096);                       \
            gl_lds16(gSrc + 96 * DIM + (k0), bD + 6144);                       \
            gl_lds16(uSrc + (k0),            bD + 8192);                       \
            gl_lds16(uSrc + 32 * DIM + (k0), bD + 10240);                      \
            gl_lds16(uSrc + 64 * DIM + (k0), bD + 12288);                      \
            gl_lds16(uSrc + 96 * DIM + (k0), bD + 14336);                      \
        } while (0)

    P1_STAGE(0, 0);
    __syncthreads();

    int cur = 0;
    for (int k0 = 0; k0 < DIM; k0 += 64) {
        if (k0 + 64 < DIM) P1_STAGE(cur ^ 1, k0 + 64);
        const bf16* Ab = As + cur * 4096;
        const bf16* Bb = Bs + cur * 16384;
#pragma unroll
        for (int kh = 0; kh < 2; ++kh) {
            int cx = ((kh * 4 + quad) ^ mx7) * 8;
            bf16x8 a[4], bg[2], bu[2];
#pragma unroll
            for (int mg = 0; mg < 4; ++mg)
                a[mg] = *(const bf16x8*)(Ab + (mg * 16 + m) * 64 + cx);
#pragma unroll
            for (int j = 0; j < 2; ++j) {
                bg[j] = *(const bf16x8*)(Bb + (w * 32 + j * 16 + m) * 64 + cx);
                bu[j] = *(const bf16x8*)(Bb + (128 + w * 32 + j * 16 + m) * 64 + cx);
            }
#pragma unroll
            for (int j = 0; j < 2; ++j)
#pragma unroll
                for (int mg = 0; mg < 4; ++mg) {
                    aG[mg][j] = MFMA16(a[mg], bg[j], aG[mg][j]);
                    aU[mg][j] = MFMA16(a[mg], bu[j], aU[mg][j]);
                }
        }
        __syncthreads();
        cur ^= 1;
    }
    #undef P1_STAGE

    if (e < 0) {
        // shared expert: write H slice to Hs (unchanged path)
#pragma unroll
        for (int mg = 0; mg < 4; ++mg)
#pragma unroll
            for (int j = 0; j < 2; ++j)
#pragma unroll
                for (int r4 = 0; r4 < 4; ++r4) {
                    float gv = aG[mg][j][r4], uv = aU[mg][j][r4];
                    float h = gv / (1.f + __expf(-gv)) * uv;
                    hout[(size_t)(mg * 16 + quad * 4 + r4) * HS + w * 32 + j * 16 + m] = (bf16)h;
                }
        return;
    }

    // ---------------- fused routed down-projection ----------------
    // H tile [64 rows][128 k] into As (16KB), chunk-XOR swizzled (cc ^= row&7).
    bf16* Ht = As;
#pragma unroll
    for (int mg = 0; mg < 4; ++mg)
#pragma unroll
        for (int j = 0; j < 2; ++j)
#pragma unroll
            for (int r4 = 0; r4 < 4; ++r4) {
                float gv = aG[mg][j][r4], uv = aU[mg][j][r4];
                float h = gv / (1.f + __expf(-gv)) * uv;
                int row = mg * 16 + quad * 4 + r4;
                int col = w * 32 + j * 16 + m;
                int cc  = col >> 3;
                Ht[row * 128 + ((cc ^ (row & 7)) << 3) + (m & 7)] = (bf16)h;
            }

    // per-lane row scores (L2-hot scalar loads; no LDS needed)
    float scv[4][4];
#pragma unroll
    for (int mg = 0; mg < 4; ++mg)
#pragma unroll
        for (int r4 = 0; r4 < 4; ++r4) {
            int li = lbase + mg * 16 + quad * 4 + r4;
            scv[mg][r4] = (li < cnt) ? slist[(size_t)e * N_TOK + li] : 0.f;
        }

    // down-B staging: [128 n-rows][128 k] = 32KB into a Bs half, swizzled
    const bf16* wde = wd + (size_t)e * DIM * H_E;
    int trow = tid >> 4;             // 0..15
    int clog = (tid & 15) ^ (trow & 7);
    #define DB_STAGE(half, nc)                                                 \
        do {                                                                   \
            bf16* dB = Bs + (half) * 16384 + tid * 8;                          \
            const bf16* sB = wde + ((size_t)(nc) * 128 + trow) * 128 + clog * 8; \
            _Pragma("unroll")                                                  \
            for (int i = 0; i < 8; ++i)                                        \
                gl_lds16(sB + (size_t)i * 16 * 128, dB + i * 2048);            \
        } while (0)

    DB_STAGE(0, 0);
    __syncthreads();   // H writes + B chunk 0 complete

    // hoist A-fragments (depend only on ks, not n-chunk): 16 x bf16x8
    bf16x8 af[4][4];
#pragma unroll
    for (int ks = 0; ks < 4; ++ks)
#pragma unroll
        for (int mg = 0; mg < 4; ++mg)
            af[ks][mg] = *(const bf16x8*)(Ht + (mg * 16 + m) * 128 +
                                          ((ks * 4 + quad) ^ (m & 7)) * 8);

    for (int nc = 0; nc < 8; ++nc) {
        if (nc + 1 < 8) DB_STAGE((nc + 1) & 1, nc + 1);
        const bf16* Bh = Bs + (nc & 1) * 16384;
        floatx4 dacc[4][2] = {{{0}}};
#pragma unroll
        for (int ks = 0; ks < 4; ++ks) {
            bf16x8 bb[2];
#pragma unroll
            for (int ng = 0; ng < 2; ++ng)
                bb[ng] = *(const bf16x8*)(Bh + (w * 32 + ng * 16 + m) * 128 +
                                          ((ks * 4 + quad) ^ (m & 7)) * 8);
#pragma unroll
            for (int ng = 0; ng < 2; ++ng)
#pragma unroll
                for (int mg = 0; mg < 4; ++mg)
                    dacc[mg][ng] = MFMA16(af[ks][mg], bb[ng], dacc[mg][ng]);
        }
#pragma unroll
        for (int mg = 0; mg < 4; ++mg)
#pragma unroll
            for (int r4 = 0; r4 < 4; ++r4) {
                int row = mg * 16 + quad * 4 + r4;
                float sc = scv[mg][r4];
                bf16* op = Od + (size_t)(rowbase + row) * DIM + nc * 128 + w * 32 + m;
                op[0]  = (bf16)(dacc[mg][0][r4] * sc);
                op[16] = (bf16)(dacc[mg][1][r4] * sc);
            }
        __syncthreads();
    }
    #undef DB_STAGE
}

// ---------------------------------------------------------------- shared down + routed reduce (R4 config + XCD chunking)
__global__ __launch_bounds__(256, 4)
void shared_down(const bf16* __restrict__ Hs, const bf16* __restrict__ sd,
                 const bf16* __restrict__ Od, const int* __restrict__ tok2slot,
                 const int* __restrict__ expbase, float* __restrict__ out) {
    __shared__ __align__(16) bf16 As[2 * 64 * 32];
    __shared__ __align__(16) bf16 Bs[2 * 256 * 32];
    __shared__ int srow[64][4];

    int t0 = xcd_swz(blockIdx.x, 128) * 64;
    int n0 = blockIdx.y * 256;
    int tid = threadIdx.x;

    if (tid < 64) {
        const int* t2s = tok2slot + (size_t)(t0 + tid) * 4;
#pragma unroll
        for (int k = 0; k < 4; ++k) {
            int v = t2s[k];
            srow[tid][k] = expbase[v >> 16] + (v & 0xffff);
        }
    }

    int r = tid >> 2;
    int chunk = (((tid & 3) ^ ((tid >> 3) & 3))) * 8;
    const bf16* aSrc = Hs + (size_t)(t0 + r) * HS + chunk;
    const bf16* bSrc = sd + (size_t)(n0 + r) * HS + chunk;

    int w = tid >> 6, lane = tid & 63, m = lane & 15, quad = lane >> 4;
    int quadx = quad ^ ((m >> 1) & 3);
    floatx4 acc[4][4] = {{{0}}};

    #define SD_STAGE(buf, k0)                                                  \
        do {                                                                   \
            bf16* aD = As + (buf) * 2048 + tid * 8;                            \
            bf16* bD = Bs + (buf) * 8192 + tid * 8;                            \
            gl_lds16(aSrc + (k0), aD);                                         \
            _Pragma("unroll")                                                  \
            for (int p = 0; p < 4; ++p)                                        \
                gl_lds16(bSrc + (size_t)p * 64 * HS + (k0), bD + p * 2048);    \
        } while (0)

    SD_STAGE(0, 0);
    __syncthreads();

    int cur = 0;
    for (int tt = 0; tt < 16; ++tt) {
        if (tt < 15) SD_STAGE(cur ^ 1, (tt + 1) * 32);
        const bf16* Ab = As + cur * 2048;
        const bf16* Bb = Bs + cur * 8192;
        bf16x8 a[4], bb[4];
#pragma unroll
        for (int mg = 0; mg < 4; ++mg)
            a[mg] = *(const bf16x8*)(Ab + (mg * 16 + m) * 32 + quadx * 8);
#pragma unroll
        for (int ng = 0; ng < 4; ++ng)
            bb[ng] = *(const bf16x8*)(Bb + (w * 64 + ng * 16 + m) * 32 + quadx * 8);
#pragma unroll
        for (int ng = 0; ng < 4; ++ng)
#pragma unroll
            for (int mg = 0; mg < 4; ++mg)
                acc[mg][ng] = MFMA16(a[mg], bb[ng], acc[mg][ng]);
        __syncthreads();
        cur ^= 1;
    }
    #undef SD_STAGE

#pragma unroll
    for (int mg = 0; mg < 4; ++mg)
#pragma unroll
        for (int r4 = 0; r4 < 4; ++r4) {
            int rl = mg * 16 + quad * 4 + r4;
            size_t r0 = (size_t)srow[rl][0] * DIM;
            size_t r1 = (size_t)srow[rl][1] * DIM;
            size_t r2 = (size_t)srow[rl][2] * DIM;
            size_t r3 = (size_t)srow[rl][3] * DIM;
            float* op = out + (size_t)(t0 + rl) * DIM + n0 + w * 64 + m;
#pragma unroll
            for (int ng = 0; ng < 4; ++ng) {
                int col = n0 + w * 64 + ng * 16 + m;
                float v = acc[mg][ng][r4]
                        + (float)Od[r0 + col] + (float)Od[r1 + col]
                        + (float)Od[r2 + col] + (float)Od[r3 + col];
                op[ng * 16] = v;
            }
        }
}

// ---------------------------------------------------------------- launch
extern "C" void kernel_launch(void* const* d_in, const int* in_sizes, int n_in,
                              void* d_out, int out_size, void* d_ws, size_t ws_size,
                              hipStream_t stream) {
    (void)in_sizes; (void)n_in; (void)out_size; (void)ws_size;
    const float* x   = (const float*)d_in[0];
    const float* rw  = (const float*)d_in[1];
    const float* rb  = (const float*)d_in[2];
    const float* gw  = (const float*)d_in[3];
    const float* uw  = (const float*)d_in[4];
    const float* dw  = (const float*)d_in[5];
    const float* sgw = (const float*)d_in[6];
    const float* suw = (const float*)d_in[7];
    const float* sdw = (const float*)d_in[8];
    float* out = (float*)d_out;

    char* ws = (char*)d_ws;
    size_t o = 0;
    bf16* xb  = (bf16*)(ws + o); o += (size_t)N_TOK * DIM * 2;
    bf16* wgb = (bf16*)(ws + o); o += (size_t)E_R * H_E * DIM * 2;
    bf16* wub = (bf16*)(ws + o); o += (size_t)E_R * H_E * DIM * 2;
    bf16* wdb = (bf16*)(ws + o); o += (size_t)E_R * DIM * H_E * 2;
    bf16* sgb = (bf16*)(ws + o); o += (size_t)HS * DIM * 2;
    bf16* sub = (bf16*)(ws + o); o += (size_t)HS * DIM * 2;
    bf16* sdb = (bf16*)(ws + o); o += (size_t)DIM * HS * 2;
    bf16* Hs  = (bf16*)(ws + o); o += (size_t)N_TOK * HS * 2;
    bf16* Od  = (bf16*)(ws + o); o += (size_t)MAXSLOT * DIM * 2;
    float* partial = (float*)(ws + o); o += (size_t)RKS * N_TOK * 32 * 4;
    int*   counts = (int*)(ws + o);   o += 256;
    int*   tlist  = (int*)(ws + o);   o += (size_t)E_R * N_TOK * 4;
    float* slist  = (float*)(ws + o); o += (size_t)E_R * N_TOK * 4;
    int*   tok2slot = (int*)(ws + o); o += (size_t)N_TOK * 4 * 4;
    int*   items  = (int*)(ws + o);   o += 4096;
    int*   nitems = (int*)(ws + o);   o += 64;
    int*   expbase = (int*)(ws + o);  o += 256;

    hipMemsetAsync(counts, 0, E_R * sizeof(int), stream);

    router_gemm<<<dim3(N_TOK / 64, RKS), 256, 0, stream>>>(x, rw, partial);
    router_fin<<<N_TOK / 256, 256, 0, stream>>>(partial, rb, counts, tlist, slist,
                                                tok2slot);
    cvt_all<<<11008, 256, 0, stream>>>(x, gw, uw, dw, sgw, suw, sdw,
                                       xb, wgb, wub, wdb, sgb, sub, sdb);
    wq_build<<<1, 64, 0, stream>>>(counts, items, nitems, expbase);
    // fused: gate/up + routed down (phase2 eliminated)
    phase1<<<1056, 256, 0, stream>>>(xb, wgb, wub, sgb, sub, wdb, counts, tlist,
                                     slist, items, nitems, Hs, Od);
    shared_down<<<dim3(N_TOK / 64, 4), 256, 0, stream>>>(Hs, sdb, Od, tok2slot,
                                                         expbase, out);
}

// Round 10
// 300.008 us; speedup vs baseline: 1.0431x; 1.0431x over previous
//
#include <hip/hip_runtime.h>
#include <hip/hip_bf16.h>
#include <math.h>

#define N_TOK 8192
#define DIM   1024
#define E_R   32
#define H_E   128
#define HS    512
#define TOPK  4
#define RKS   8            // router K-splits
#define RKL   (DIM / RKS)  // 128 K per split
#define MAXSLOT 34816

typedef __bf16 bf16;
typedef __bf16 bf16x8 __attribute__((ext_vector_type(8)));
typedef float  floatx4 __attribute__((ext_vector_type(4)));

#define MFMA16(a,b,c) __builtin_amdgcn_mfma_f32_16x16x32_bf16(a,b,c,0,0,0)

__device__ __forceinline__ void gl_lds16(const bf16* g, bf16* l) {
    __builtin_amdgcn_global_load_lds(
        (const __attribute__((address_space(1))) void*)g,
        (__attribute__((address_space(3))) void*)l, 16, 0, 0);
}

// XCD-chunked bijective swizzle (m204): each XCD owns a contiguous logical
// block range -> blocks sharing weight panels hit the same L2. (R8: -32% FETCH)
__device__ __forceinline__ int xcd_swz(int b, int n) {
    int q = n >> 3, r = n & 7;
    int xcd = b & 7, idx = b >> 3;
    return (xcd < r ? xcd * (q + 1) : r * (q + 1) + (xcd - r) * q) + idx;
}

// ---------------------------------------------------------------- fused convert
__global__ __launch_bounds__(256)
void cvt_all(const float* __restrict__ x, const float* __restrict__ g,
             const float* __restrict__ u, const float* __restrict__ d,
             const float* __restrict__ sg, const float* __restrict__ su,
             const float* __restrict__ sd,
             bf16* __restrict__ xb, bf16* __restrict__ gb, bf16* __restrict__ ub,
             bf16* __restrict__ db, bf16* __restrict__ sgb, bf16* __restrict__ sub,
             bf16* __restrict__ sdb) {
    int b = blockIdx.x;
    const float* s; bf16* o; int lb;
    if      (b < 4096)  { s = x;  o = xb;  lb = b; }
    else if (b < 6144)  { s = g;  o = gb;  lb = b - 4096; }
    else if (b < 8192)  { s = u;  o = ub;  lb = b - 6144; }
    else if (b < 10240) { s = d;  o = db;  lb = b - 8192; }
    else if (b < 10496) { s = sg; o = sgb; lb = b - 10240; }
    else if (b < 10752) { s = su; o = sub; lb = b - 10496; }
    else                { s = sd; o = sdb; lb = b - 10752; }
    size_t i = (size_t)lb * 2048 + threadIdx.x * 8;
    float4 v0 = *(const float4*)(s + i);
    float4 v1 = *(const float4*)(s + i + 4);
    bf16x8 r = {(bf16)v0.x,(bf16)v0.y,(bf16)v0.z,(bf16)v0.w,
                (bf16)v1.x,(bf16)v1.y,(bf16)v1.z,(bf16)v1.w};
    *(bf16x8*)(o + i) = r;
}

// ---------------------------------------------------------------- router v4: LDS-staged K-split GEMM
__global__ __launch_bounds__(256)
void router_gemm(const float* __restrict__ x, const float* __restrict__ rw,
                 float* __restrict__ partial) {
    __shared__ float Xs[64 * 132];
    __shared__ float Wt[128 * 32];
    int tid = threadIdx.x;
    int t0  = blockIdx.x * 64;
    int kb  = blockIdx.y * RKL;

#pragma unroll
    for (int j = 0; j < 8; ++j) {
        int flat = j * 1024 + tid * 4;
        int row = flat >> 7, col = flat & 127;
        float4 v = *(const float4*)(x + (size_t)(t0 + row) * DIM + kb + col);
        *(float4*)(&Xs[row * 132 + col]) = v;
    }
    {
        int e = tid >> 3, kq = (tid & 7) * 16;
        const float* wp = rw + (size_t)e * DIM + kb + kq;
#pragma unroll
        for (int i = 0; i < 16; i += 4) {
            float4 v = *(const float4*)(wp + i);
            Wt[(kq + i + 0) * 32 + e] = v.x;
            Wt[(kq + i + 1) * 32 + e] = v.y;
            Wt[(kq + i + 2) * 32 + e] = v.z;
            Wt[(kq + i + 3) * 32 + e] = v.w;
        }
    }
    __syncthreads();

    int eg = tid & 7, tg = tid >> 3;
    float acc[2][4] = {{0.f}};
#pragma unroll 4
    for (int k = 0; k < RKL; k += 4) {
        float4 xa0 = *(const float4*)(&Xs[(tg * 2 + 0) * 132 + k]);
        float4 xa1 = *(const float4*)(&Xs[(tg * 2 + 1) * 132 + k]);
#pragma unroll
        for (int kk = 0; kk < 4; ++kk) {
            float4 w = *(const float4*)(&Wt[(k + kk) * 32 + eg * 4]);
            float x0 = (&xa0.x)[kk], x1 = (&xa1.x)[kk];
            acc[0][0] += x0 * w.x; acc[0][1] += x0 * w.y;
            acc[0][2] += x0 * w.z; acc[0][3] += x0 * w.w;
            acc[1][0] += x1 * w.x; acc[1][1] += x1 * w.y;
            acc[1][2] += x1 * w.z; acc[1][3] += x1 * w.w;
        }
    }
#pragma unroll
    for (int t = 0; t < 2; ++t) {
        floatx4 v = { acc[t][0], acc[t][1], acc[t][2], acc[t][3] };
        *(floatx4*)(&partial[((size_t)blockIdx.y * N_TOK + t0 + tg * 2 + t) * 32 + eg * 4]) = v;
    }
}

// ---------------------------------------------------------------- router finalize
__global__ __launch_bounds__(256)
void router_fin(const float* __restrict__ partial, const float* __restrict__ rb,
                int* __restrict__ counts, int* __restrict__ tlist,
                float* __restrict__ slist, int* __restrict__ klist) {
    __shared__ int lcnt[E_R];
    __shared__ int gbase[E_R];
    int tid = threadIdx.x;
    int n = blockIdx.x * 256 + tid;
    if (tid < E_R) lcnt[tid] = 0;
    __syncthreads();

    float lg[E_R];
#pragma unroll
    for (int e4 = 0; e4 < E_R; e4 += 4) {
        floatx4 s = {0.f, 0.f, 0.f, 0.f};
#pragma unroll
        for (int ks = 0; ks < RKS; ++ks)
            s += *(const floatx4*)(&partial[((size_t)ks * N_TOK + n) * 32 + e4]);
        lg[e4 + 0] = s[0] + rb[e4 + 0];
        lg[e4 + 1] = s[1] + rb[e4 + 1];
        lg[e4 + 2] = s[2] + rb[e4 + 2];
        lg[e4 + 3] = s[3] + rb[e4 + 3];
    }
    float mx = -1e30f;
#pragma unroll
    for (int e = 0; e < E_R; ++e) mx = fmaxf(mx, lg[e]);
    float se = 0.f;
#pragma unroll
    for (int e = 0; e < E_R; ++e) { float v = __expf(lg[e] - mx); lg[e] = v; se += v; }
    float inv = 1.f / se;

    unsigned usedMask = 0;
    int idx[TOPK]; float pv[TOPK]; int lpos[TOPK]; float psum = 0.f;
    for (int k = 0; k < TOPK; ++k) {
        float best = -1.f; int bi = 0;
        for (int e = 0; e < E_R; ++e)
            if (!((usedMask >> e) & 1) && lg[e] > best) { best = lg[e]; bi = e; }
        usedMask |= 1u << bi;
        idx[k] = bi; pv[k] = best * inv; psum += pv[k];
    }
    float norm = 1.f / fmaxf(psum, 1e-12f);
#pragma unroll
    for (int k = 0; k < TOPK; ++k)
        lpos[k] = atomicAdd(&lcnt[idx[k]], 1);
    __syncthreads();
    if (tid < E_R) gbase[tid] = atomicAdd(&counts[tid], lcnt[tid]);
    __syncthreads();
#pragma unroll
    for (int k = 0; k < TOPK; ++k) {
        int e = idx[k];
        int pos = gbase[e] + lpos[k];
        tlist[(size_t)e * N_TOK + pos] = n;
        slist[(size_t)e * N_TOK + pos] = pv[k] * norm;
        klist[(size_t)e * N_TOK + pos] = k;
    }
}

// ---------------------------------------------------------------- work-queue build
__global__ void wq_build(const int* __restrict__ counts, int* __restrict__ items,
                         int* __restrict__ nitems) {
    if (threadIdx.x == 0) {
        int n = 0, base = 0;
        for (int e = 0; e < E_R; ++e) {
            int c = counts[e];
            int nt = (c + 63) >> 6;
            for (int t = 0; t < nt; ++t)
                items[n++] = (e << 24) | (t << 16) | (base + t * 64);
            base += nt * 64;
        }
        *nitems = n;
    }
}

// ---------------------------------------------------------------- phase 1 (BK=64, dbuf, swizzle, XCD-chunked; R8 best)
__global__ __launch_bounds__(256, 2)
void phase1(const bf16* __restrict__ xb, const bf16* __restrict__ wg,
            const bf16* __restrict__ wu, const bf16* __restrict__ sg,
            const bf16* __restrict__ su, const int* __restrict__ counts,
            const int* __restrict__ tlist, const int* __restrict__ items,
            const int* __restrict__ nitems,
            bf16* __restrict__ Hg, bf16* __restrict__ Hs) {
    __shared__ __align__(16) bf16 As[2 * 64 * 64];
    __shared__ __align__(16) bf16 Bs[2 * 256 * 64];

    int b = xcd_swz(blockIdx.x, 1056);
    const bf16 *gptr, *uptr;
    bf16* hout; int hstride;
    int e, lbase, cnt = 0;
    if (b < 512) {
        int c = b >> 7, t = b & 127;
        gptr = sg + (size_t)c * H_E * DIM;
        uptr = su + (size_t)c * H_E * DIM;
        hout = Hs + (size_t)t * 64 * HS + c * H_E;
        hstride = HS;
        lbase = t * 64;
        e = -1;
    } else {
        int rbk = b - 512;
        if (rbk >= *nitems) return;
        int it = items[rbk];
        e = it >> 24; int t = (it >> 16) & 0xff; int rowbase = it & 0xffff;
        gptr = wg + (size_t)e * H_E * DIM;
        uptr = wu + (size_t)e * H_E * DIM;
        hout = Hg + (size_t)rowbase * H_E;
        hstride = H_E;
        cnt = counts[e];
        lbase = t * 64;
    }

    int tid = threadIdx.x;
    int rs = tid >> 3;                               // staging row in 32-row group
    int cOff = ((tid & 7) ^ (rs & 7)) * 8;           // pre-swizzled global chunk
    int tokA, tokB;
    if (e < 0) { tokA = lbase + rs; tokB = lbase + rs + 32; }
    else {
        int liA = lbase + rs;      if (liA >= cnt) liA = cnt - 1;
        int liB = lbase + rs + 32; if (liB >= cnt) liB = cnt - 1;
        tokA = tlist[(size_t)e * N_TOK + liA];
        tokB = tlist[(size_t)e * N_TOK + liB];
    }
    const bf16* aSrc0 = xb + (size_t)tokA * DIM + cOff;
    const bf16* aSrc1 = xb + (size_t)tokB * DIM + cOff;
    const bf16* gSrc  = gptr + (size_t)rs * DIM + cOff;
    const bf16* uSrc  = uptr + (size_t)rs * DIM + cOff;

    int w = tid >> 6, lane = tid & 63, m = lane & 15, quad = lane >> 4;
    int mx7 = m & 7;

    floatx4 aG[4][2] = {{{0}}};
    floatx4 aU[4][2] = {{{0}}};

    #define P1_STAGE(buf, k0)                                                  \
        do {                                                                   \
            bf16* aD = As + (buf) * 4096 + tid * 8;                            \
            bf16* bD = Bs + (buf) * 16384 + tid * 8;                           \
            gl_lds16(aSrc0 + (k0), aD);                                        \
            gl_lds16(aSrc1 + (k0), aD + 2048);                                 \
            gl_lds16(gSrc + (k0),            bD);                              \
            gl_lds16(gSrc + 32 * DIM + (k0), bD + 2048);                       \
            gl_lds16(gSrc + 64 * DIM + (k0), bD + 4096);                       \
            gl_lds16(gSrc + 96 * DIM + (k0), bD + 6144);                       \
            gl_lds16(uSrc + (k0),            bD + 8192);                       \
            gl_lds16(uSrc + 32 * DIM + (k0), bD + 10240);                      \
            gl_lds16(uSrc + 64 * DIM + (k0), bD + 12288);                      \
            gl_lds16(uSrc + 96 * DIM + (k0), bD + 14336);                      \
        } while (0)

    P1_STAGE(0, 0);
    __syncthreads();

    int cur = 0;
    for (int k0 = 0; k0 < DIM; k0 += 64) {
        if (k0 + 64 < DIM) P1_STAGE(cur ^ 1, k0 + 64);
        const bf16* Ab = As + cur * 4096;
        const bf16* Bb = Bs + cur * 16384;
#pragma unroll
        for (int kh = 0; kh < 2; ++kh) {
            int cx = ((kh * 4 + quad) ^ mx7) * 8;
            bf16x8 a[4], bg[2], bu[2];
#pragma unroll
            for (int mg = 0; mg < 4; ++mg)
                a[mg] = *(const bf16x8*)(Ab + (mg * 16 + m) * 64 + cx);
#pragma unroll
            for (int j = 0; j < 2; ++j) {
                bg[j] = *(const bf16x8*)(Bb + (w * 32 + j * 16 + m) * 64 + cx);
                bu[j] = *(const bf16x8*)(Bb + (128 + w * 32 + j * 16 + m) * 64 + cx);
            }
#pragma unroll
            for (int j = 0; j < 2; ++j)
#pragma unroll
                for (int mg = 0; mg < 4; ++mg) {
                    aG[mg][j] = MFMA16(a[mg], bg[j], aG[mg][j]);
                    aU[mg][j] = MFMA16(a[mg], bu[j], aU[mg][j]);
                }
        }
        __syncthreads();
        cur ^= 1;
    }
    #undef P1_STAGE

#pragma unroll
    for (int mg = 0; mg < 4; ++mg)
#pragma unroll
        for (int j = 0; j < 2; ++j)
#pragma unroll
            for (int r4 = 0; r4 < 4; ++r4) {
                float gv = aG[mg][j][r4], uv = aU[mg][j][r4];
                float h = gv / (1.f + __expf(-gv)) * uv;
                hout[(size_t)(mg * 16 + quad * 4 + r4) * hstride + w * 32 + j * 16 + m] = (bf16)h;
            }
}

// ---------------------------------------------------------------- phase 2 (routed down -> token-major Od2)
__global__ __launch_bounds__(256, 4)
void phase2(const bf16* __restrict__ Hg, const bf16* __restrict__ wd,
            const int* __restrict__ counts, const float* __restrict__ slist,
            const int* __restrict__ tlist, const int* __restrict__ klist,
            const int* __restrict__ items, const int* __restrict__ nitems,
            bf16* __restrict__ Od2) {
    __shared__ __align__(16) bf16 As[2 * 64 * 32];
    __shared__ __align__(16) bf16 Bs[2 * 256 * 32];
    __shared__ float ssc[64];
    __shared__ int   srw[64];    // tok*4 + k (token-major Od2 row); -1 = padding

    int rbk = xcd_swz(blockIdx.x, 544);
    if (rbk >= *nitems) return;
    int it = items[rbk];
    int e = it >> 24, t = (it >> 16) & 0xff, rowbase = it & 0xffff;
    int n0 = blockIdx.y * 256;
    int cnt = counts[e];

    int tid = threadIdx.x;
    if (tid < 64) {
        int li = t * 64 + tid;
        bool ok = (li < cnt);
        ssc[tid] = ok ? slist[(size_t)e * N_TOK + li] : 0.f;
        srw[tid] = ok ? tlist[(size_t)e * N_TOK + li] * 4 +
                        klist[(size_t)e * N_TOK + li] : -1;
    }

    int r = tid >> 2;
    int chunk = (((tid & 3) ^ ((tid >> 3) & 3))) * 8;
    const bf16* aSrc = Hg + (size_t)(rowbase + r) * H_E + chunk;
    const bf16* bSrc = wd + (size_t)e * DIM * H_E + (size_t)(n0 + r) * H_E + chunk;

    int w = tid >> 6, lane = tid & 63, m = lane & 15, quad = lane >> 4;
    int quadx = quad ^ ((m >> 1) & 3);
    floatx4 acc[4][4] = {{{0}}};

    #define P2_STAGE(buf, k0)                                                  \
        do {                                                                   \
            bf16* aD = As + (buf) * 2048 + tid * 8;                            \
            bf16* bD = Bs + (buf) * 8192 + tid * 8;                            \
            gl_lds16(aSrc + (k0), aD);                                         \
            _Pragma("unroll")                                                  \
            for (int p = 0; p < 4; ++p)                                        \
                gl_lds16(bSrc + (size_t)p * 64 * H_E + (k0), bD + p * 2048);   \
        } while (0)

    P2_STAGE(0, 0);
    __syncthreads();

    int cur = 0;
    for (int k0 = 0; k0 < H_E; k0 += 32) {
        if (k0 + 32 < H_E) P2_STAGE(cur ^ 1, k0 + 32);
        const bf16* Ab = As + cur * 2048;
        const bf16* Bb = Bs + cur * 8192;
        bf16x8 a[4], bb[4];
#pragma unroll
        for (int mg = 0; mg < 4; ++mg)
            a[mg] = *(const bf16x8*)(Ab + (mg * 16 + m) * 32 + quadx * 8);
#pragma unroll
        for (int ng = 0; ng < 4; ++ng)
            bb[ng] = *(const bf16x8*)(Bb + (w * 64 + ng * 16 + m) * 32 + quadx * 8);
#pragma unroll
        for (int ng = 0; ng < 4; ++ng)
#pragma unroll
            for (int mg = 0; mg < 4; ++mg)
                acc[mg][ng] = MFMA16(a[mg], bb[ng], acc[mg][ng]);
        __syncthreads();
        cur ^= 1;
    }
    #undef P2_STAGE

#pragma unroll
    for (int mg = 0; mg < 4; ++mg)
#pragma unroll
        for (int r4 = 0; r4 < 4; ++r4) {
            int row = mg * 16 + quad * 4 + r4;
            int orow = srw[row];
            if (orow < 0) continue;          // padding slot: no output row
            float sc = ssc[row];
            bf16* op = Od2 + (size_t)orow * DIM + n0 + w * 64 + m;
#pragma unroll
            for (int ng = 0; ng < 4; ++ng)
                op[ng * 16] = (bf16)(acc[mg][ng][r4] * sc);
        }
}

// ---------------------------------------------------------------- shared down + sequential routed reduce
__global__ __launch_bounds__(256, 4)
void shared_down(const bf16* __restrict__ Hs, const bf16* __restrict__ sd,
                 const bf16* __restrict__ Od2, float* __restrict__ out) {
    __shared__ __align__(16) bf16 As[2 * 64 * 32];
    __shared__ __align__(16) bf16 Bs[2 * 256 * 32];

    int t0 = xcd_swz(blockIdx.x, 128) * 64;
    int n0 = blockIdx.y * 256;
    int tid = threadIdx.x;

    int r = tid >> 2;
    int chunk = (((tid & 3) ^ ((tid >> 3) & 3))) * 8;
    const bf16* aSrc = Hs + (size_t)(t0 + r) * HS + chunk;
    const bf16* bSrc = sd + (size_t)(n0 + r) * HS + chunk;

    int w = tid >> 6, lane = tid & 63, m = lane & 15, quad = lane >> 4;
    int quadx = quad ^ ((m >> 1) & 3);
    floatx4 acc[4][4] = {{{0}}};

    #define SD_STAGE(buf, k0)                                                  \
        do {                                                                   \
            bf16* aD = As + (buf) * 2048 + tid * 8;                            \
            bf16* bD = Bs + (buf) * 8192 + tid * 8;                            \
            gl_lds16(aSrc + (k0), aD);                                         \
            _Pragma("unroll")                                                  \
            for (int p = 0; p < 4; ++p)                                        \
                gl_lds16(bSrc + (size_t)p * 64 * HS + (k0), bD + p * 2048);    \
        } while (0)

    SD_STAGE(0, 0);
    __syncthreads();

    int cur = 0;
    for (int tt = 0; tt < 16; ++tt) {
        if (tt < 15) SD_STAGE(cur ^ 1, (tt + 1) * 32);
        const bf16* Ab = As + cur * 2048;
        const bf16* Bb = Bs + cur * 8192;
        bf16x8 a[4], bb[4];
#pragma unroll
        for (int mg = 0; mg < 4; ++mg)
            a[mg] = *(const bf16x8*)(Ab + (mg * 16 + m) * 32 + quadx * 8);
#pragma unroll
        for (int ng = 0; ng < 4; ++ng)
            bb[ng] = *(const bf16x8*)(Bb + (w * 64 + ng * 16 + m) * 32 + quadx * 8);
#pragma unroll
        for (int ng = 0; ng < 4; ++ng)
#pragma unroll
            for (int mg = 0; mg < 4; ++mg)
                acc[mg][ng] = MFMA16(a[mg], bb[ng], acc[mg][ng]);
        __syncthreads();
        cur ^= 1;
    }
    #undef SD_STAGE

#pragma unroll
    for (int mg = 0; mg < 4; ++mg)
#pragma unroll
        for (int r4 = 0; r4 < 4; ++r4) {
            int rl = mg * 16 + quad * 4 + r4;
            // token-major Od2: 4 consecutive rows per token -> streaming reads
            const bf16* og = Od2 + (size_t)(t0 + rl) * 4 * DIM;
            float* op = out + (size_t)(t0 + rl) * DIM + n0 + w * 64 + m;
#pragma unroll
            for (int ng = 0; ng < 4; ++ng) {
                int col = n0 + w * 64 + ng * 16 + m;
                float v = acc[mg][ng][r4]
                        + (float)og[col] + (float)og[DIM + col]
                        + (float)og[2 * DIM + col] + (float)og[3 * DIM + col];
                op[ng * 16] = v;
            }
        }
}

// ---------------------------------------------------------------- launch
extern "C" void kernel_launch(void* const* d_in, const int* in_sizes, int n_in,
                              void* d_out, int out_size, void* d_ws, size_t ws_size,
                              hipStream_t stream) {
    (void)in_sizes; (void)n_in; (void)out_size; (void)ws_size;
    const float* x   = (const float*)d_in[0];
    const float* rw  = (const float*)d_in[1];
    const float* rb  = (const float*)d_in[2];
    const float* gw  = (const float*)d_in[3];
    const float* uw  = (const float*)d_in[4];
    const float* dw  = (const float*)d_in[5];
    const float* sgw = (const float*)d_in[6];
    const float* suw = (const float*)d_in[7];
    const float* sdw = (const float*)d_in[8];
    float* out = (float*)d_out;

    char* ws = (char*)d_ws;
    size_t o = 0;
    bf16* xb  = (bf16*)(ws + o); o += (size_t)N_TOK * DIM * 2;
    bf16* wgb = (bf16*)(ws + o); o += (size_t)E_R * H_E * DIM * 2;
    bf16* wub = (bf16*)(ws + o); o += (size_t)E_R * H_E * DIM * 2;
    bf16* wdb = (bf16*)(ws + o); o += (size_t)E_R * DIM * H_E * 2;
    bf16* sgb = (bf16*)(ws + o); o += (size_t)HS * DIM * 2;
    bf16* sub = (bf16*)(ws + o); o += (size_t)HS * DIM * 2;
    bf16* sdb = (bf16*)(ws + o); o += (size_t)DIM * HS * 2;
    bf16* Hg  = (bf16*)(ws + o); o += (size_t)MAXSLOT * H_E * 2;
    bf16* Hs  = (bf16*)(ws + o); o += (size_t)N_TOK * HS * 2;
    bf16* Od2 = (bf16*)(ws + o); o += (size_t)N_TOK * 4 * DIM * 2;
    float* partial = (float*)(ws + o); o += (size_t)RKS * N_TOK * 32 * 4;
    int*   counts = (int*)(ws + o);   o += 256;
    int*   tlist  = (int*)(ws + o);   o += (size_t)E_R * N_TOK * 4;
    float* slist  = (float*)(ws + o); o += (size_t)E_R * N_TOK * 4;
    int*   klist  = (int*)(ws + o);   o += (size_t)E_R * N_TOK * 4;
    int*   items  = (int*)(ws + o);   o += 4096;
    int*   nitems = (int*)(ws + o);   o += 64;

    hipMemsetAsync(counts, 0, E_R * sizeof(int), stream);

    router_gemm<<<dim3(N_TOK / 64, RKS), 256, 0, stream>>>(x, rw, partial);
    router_fin<<<N_TOK / 256, 256, 0, stream>>>(partial, rb, counts, tlist, slist,
                                                klist);
    cvt_all<<<11008, 256, 0, stream>>>(x, gw, uw, dw, sgw, suw, sdw,
                                       xb, wgb, wub, wdb, sgb, sub, sdb);
    wq_build<<<1, 64, 0, stream>>>(counts, items, nitems);
    phase1<<<1056, 256, 0, stream>>>(xb, wgb, wub, sgb, sub, counts, tlist,
                                     items, nitems, Hg, Hs);
    phase2<<<dim3(544, 4), 256, 0, stream>>>(Hg, wdb, counts, slist, tlist, klist,
                                             items, nitems, Od2);
    shared_down<<<dim3(N_TOK / 64, 4), 256, 0, stream>>>(Hs, sdb, Od2, out);
}

// Round 11
// 290.696 us; speedup vs baseline: 1.0766x; 1.0320x over previous
//
#include <hip/hip_runtime.h>
#include <hip/hip_bf16.h>
#include <math.h>

#define N_TOK 8192
#define DIM   1024
#define E_R   32
#define H_E   128
#define HS    512
#define TOPK  4
#define RKS   8            // router K-splits
#define RKL   (DIM / RKS)  // 128 K per split
#define MAXSLOT 34816

typedef __bf16 bf16;
typedef __bf16 bf16x4 __attribute__((ext_vector_type(4)));
typedef __bf16 bf16x8 __attribute__((ext_vector_type(8)));
typedef float  floatx4 __attribute__((ext_vector_type(4)));

#define MFMA16(a,b,c) __builtin_amdgcn_mfma_f32_16x16x32_bf16(a,b,c,0,0,0)

__device__ __forceinline__ void gl_lds16(const bf16* g, bf16* l) {
    __builtin_amdgcn_global_load_lds(
        (const __attribute__((address_space(1))) void*)g,
        (__attribute__((address_space(3))) void*)l, 16, 0, 0);
}

// XCD-chunked bijective swizzle (m204): each XCD owns a contiguous logical
// block range -> blocks sharing weight panels hit the same L2. (R8: -32% FETCH)
__device__ __forceinline__ int xcd_swz(int b, int n) {
    int q = n >> 3, r = n & 7;
    int xcd = b & 7, idx = b >> 3;
    return (xcd < r ? xcd * (q + 1) : r * (q + 1) + (xcd - r) * q) + idx;
}

// ---------------------------------------------------------------- fused convert (weights only; x handled by router_gemm)
__global__ __launch_bounds__(256)
void cvt_all(const float* __restrict__ g,
             const float* __restrict__ u, const float* __restrict__ d,
             const float* __restrict__ sg, const float* __restrict__ su,
             const float* __restrict__ sd,
             bf16* __restrict__ gb, bf16* __restrict__ ub,
             bf16* __restrict__ db, bf16* __restrict__ sgb, bf16* __restrict__ sub,
             bf16* __restrict__ sdb) {
    int b = blockIdx.x;
    const float* s; bf16* o; int lb;
    if      (b < 2048)  { s = g;  o = gb;  lb = b; }
    else if (b < 4096)  { s = u;  o = ub;  lb = b - 2048; }
    else if (b < 6144)  { s = d;  o = db;  lb = b - 4096; }
    else if (b < 6400)  { s = sg; o = sgb; lb = b - 6144; }
    else if (b < 6656)  { s = su; o = sub; lb = b - 6400; }
    else                { s = sd; o = sdb; lb = b - 6656; }
    size_t i = (size_t)lb * 2048 + threadIdx.x * 8;
    float4 v0 = *(const float4*)(s + i);
    float4 v1 = *(const float4*)(s + i + 4);
    bf16x8 r = {(bf16)v0.x,(bf16)v0.y,(bf16)v0.z,(bf16)v0.w,
                (bf16)v1.x,(bf16)v1.y,(bf16)v1.z,(bf16)v1.w};
    *(bf16x8*)(o + i) = r;
}

// ---------------------------------------------------------------- router GEMM (+ fused x->bf16 emit)
// Grid covers x exactly once (tokens x k-splits) -> emit xb as a side product
// while the fp32 values are already in registers. Saves cvt_all's 33.5MB x pass.
__global__ __launch_bounds__(256)
void router_gemm(const float* __restrict__ x, const float* __restrict__ rw,
                 float* __restrict__ partial, bf16* __restrict__ xb) {
    __shared__ float Xs[64 * 132];
    __shared__ float Wt[128 * 32];
    int tid = threadIdx.x;
    int t0  = blockIdx.x * 64;
    int kb  = blockIdx.y * RKL;

#pragma unroll
    for (int j = 0; j < 8; ++j) {
        int flat = j * 1024 + tid * 4;
        int row = flat >> 7, col = flat & 127;
        float4 v = *(const float4*)(x + (size_t)(t0 + row) * DIM + kb + col);
        *(float4*)(&Xs[row * 132 + col]) = v;
        bf16x4 bv = {(bf16)v.x, (bf16)v.y, (bf16)v.z, (bf16)v.w};
        *(bf16x4*)(xb + (size_t)(t0 + row) * DIM + kb + col) = bv;
    }
    {
        int e = tid >> 3, kq = (tid & 7) * 16;
        const float* wp = rw + (size_t)e * DIM + kb + kq;
#pragma unroll
        for (int i = 0; i < 16; i += 4) {
            float4 v = *(const float4*)(wp + i);
            Wt[(kq + i + 0) * 32 + e] = v.x;
            Wt[(kq + i + 1) * 32 + e] = v.y;
            Wt[(kq + i + 2) * 32 + e] = v.z;
            Wt[(kq + i + 3) * 32 + e] = v.w;
        }
    }
    __syncthreads();

    int eg = tid & 7, tg = tid >> 3;
    float acc[2][4] = {{0.f}};
#pragma unroll 4
    for (int k = 0; k < RKL; k += 4) {
        float4 xa0 = *(const float4*)(&Xs[(tg * 2 + 0) * 132 + k]);
        float4 xa1 = *(const float4*)(&Xs[(tg * 2 + 1) * 132 + k]);
#pragma unroll
        for (int kk = 0; kk < 4; ++kk) {
            float4 w = *(const float4*)(&Wt[(k + kk) * 32 + eg * 4]);
            float x0 = (&xa0.x)[kk], x1 = (&xa1.x)[kk];
            acc[0][0] += x0 * w.x; acc[0][1] += x0 * w.y;
            acc[0][2] += x0 * w.z; acc[0][3] += x0 * w.w;
            acc[1][0] += x1 * w.x; acc[1][1] += x1 * w.y;
            acc[1][2] += x1 * w.z; acc[1][3] += x1 * w.w;
        }
    }
#pragma unroll
    for (int t = 0; t < 2; ++t) {
        floatx4 v = { acc[t][0], acc[t][1], acc[t][2], acc[t][3] };
        *(floatx4*)(&partial[((size_t)blockIdx.y * N_TOK + t0 + tg * 2 + t) * 32 + eg * 4]) = v;
    }
}

// ---------------------------------------------------------------- router finalize
__global__ __launch_bounds__(256)
void router_fin(const float* __restrict__ partial, const float* __restrict__ rb,
                int* __restrict__ counts, int* __restrict__ tlist,
                float* __restrict__ slist, int* __restrict__ tok2slot) {
    __shared__ int lcnt[E_R];
    __shared__ int gbase[E_R];
    int tid = threadIdx.x;
    int n = blockIdx.x * 256 + tid;
    if (tid < E_R) lcnt[tid] = 0;
    __syncthreads();

    float lg[E_R];
#pragma unroll
    for (int e4 = 0; e4 < E_R; e4 += 4) {
        floatx4 s = {0.f, 0.f, 0.f, 0.f};
#pragma unroll
        for (int ks = 0; ks < RKS; ++ks)
            s += *(const floatx4*)(&partial[((size_t)ks * N_TOK + n) * 32 + e4]);
        lg[e4 + 0] = s[0] + rb[e4 + 0];
        lg[e4 + 1] = s[1] + rb[e4 + 1];
        lg[e4 + 2] = s[2] + rb[e4 + 2];
        lg[e4 + 3] = s[3] + rb[e4 + 3];
    }
    float mx = -1e30f;
#pragma unroll
    for (int e = 0; e < E_R; ++e) mx = fmaxf(mx, lg[e]);
    float se = 0.f;
#pragma unroll
    for (int e = 0; e < E_R; ++e) { float v = __expf(lg[e] - mx); lg[e] = v; se += v; }
    float inv = 1.f / se;

    unsigned usedMask = 0;
    int idx[TOPK]; float pv[TOPK]; int lpos[TOPK]; float psum = 0.f;
    for (int k = 0; k < TOPK; ++k) {
        float best = -1.f; int bi = 0;
        for (int e = 0; e < E_R; ++e)
            if (!((usedMask >> e) & 1) && lg[e] > best) { best = lg[e]; bi = e; }
        usedMask |= 1u << bi;
        idx[k] = bi; pv[k] = best * inv; psum += pv[k];
    }
    float norm = 1.f / fmaxf(psum, 1e-12f);
#pragma unroll
    for (int k = 0; k < TOPK; ++k)
        lpos[k] = atomicAdd(&lcnt[idx[k]], 1);
    __syncthreads();
    if (tid < E_R) gbase[tid] = atomicAdd(&counts[tid], lcnt[tid]);
    __syncthreads();
#pragma unroll
    for (int k = 0; k < TOPK; ++k) {
        int e = idx[k];
        int pos = gbase[e] + lpos[k];
        tlist[(size_t)e * N_TOK + pos] = n;
        slist[(size_t)e * N_TOK + pos] = pv[k] * norm;
        tok2slot[(size_t)n * 4 + k] = (e << 16) | pos;
    }
}

// ---------------------------------------------------------------- work-queue build
__global__ void wq_build(const int* __restrict__ counts, int* __restrict__ items,
                         int* __restrict__ nitems, int* __restrict__ expbase) {
    if (threadIdx.x == 0) {
        int n = 0, base = 0;
        for (int e = 0; e < E_R; ++e) {
            int c = counts[e];
            expbase[e] = base;
            int nt = (c + 63) >> 6;
            for (int t = 0; t < nt; ++t)
                items[n++] = (e << 24) | (t << 16) | (base + t * 64);
            base += nt * 64;
        }
        *nitems = n;
    }
}

// ---------------------------------------------------------------- phase 1 (BK=64, dbuf, swizzle, XCD-chunked; R8 best)
__global__ __launch_bounds__(256, 2)
void phase1(const bf16* __restrict__ xb, const bf16* __restrict__ wg,
            const bf16* __restrict__ wu, const bf16* __restrict__ sg,
            const bf16* __restrict__ su, const int* __restrict__ counts,
            const int* __restrict__ tlist, const int* __restrict__ items,
            const int* __restrict__ nitems,
            bf16* __restrict__ Hg, bf16* __restrict__ Hs) {
    __shared__ __align__(16) bf16 As[2 * 64 * 64];
    __shared__ __align__(16) bf16 Bs[2 * 256 * 64];

    int b = xcd_swz(blockIdx.x, 1056);
    const bf16 *gptr, *uptr;
    bf16* hout; int hstride;
    int e, lbase, cnt = 0;
    if (b < 512) {
        int c = b >> 7, t = b & 127;
        gptr = sg + (size_t)c * H_E * DIM;
        uptr = su + (size_t)c * H_E * DIM;
        hout = Hs + (size_t)t * 64 * HS + c * H_E;
        hstride = HS;
        lbase = t * 64;
        e = -1;
    } else {
        int rbk = b - 512;
        if (rbk >= *nitems) return;
        int it = items[rbk];
        e = it >> 24; int t = (it >> 16) & 0xff; int rowbase = it & 0xffff;
        gptr = wg + (size_t)e * H_E * DIM;
        uptr = wu + (size_t)e * H_E * DIM;
        hout = Hg + (size_t)rowbase * H_E;
        hstride = H_E;
        cnt = counts[e];
        lbase = t * 64;
    }

    int tid = threadIdx.x;
    int rs = tid >> 3;                               // staging row in 32-row group
    int cOff = ((tid & 7) ^ (rs & 7)) * 8;           // pre-swizzled global chunk
    int tokA, tokB;
    if (e < 0) { tokA = lbase + rs; tokB = lbase + rs + 32; }
    else {
        int liA = lbase + rs;      if (liA >= cnt) liA = cnt - 1;
        int liB = lbase + rs + 32; if (liB >= cnt) liB = cnt - 1;
        tokA = tlist[(size_t)e * N_TOK + liA];
        tokB = tlist[(size_t)e * N_TOK + liB];
    }
    const bf16* aSrc0 = xb + (size_t)tokA * DIM + cOff;
    const bf16* aSrc1 = xb + (size_t)tokB * DIM + cOff;
    const bf16* gSrc  = gptr + (size_t)rs * DIM + cOff;
    const bf16* uSrc  = uptr + (size_t)rs * DIM + cOff;

    int w = tid >> 6, lane = tid & 63, m = lane & 15, quad = lane >> 4;
    int mx7 = m & 7;

    floatx4 aG[4][2] = {{{0}}};
    floatx4 aU[4][2] = {{{0}}};

    #define P1_STAGE(buf, k0)                                                  \
        do {                                                                   \
            bf16* aD = As + (buf) * 4096 + tid * 8;                            \
            bf16* bD = Bs + (buf) * 16384 + tid * 8;                           \
            gl_lds16(aSrc0 + (k0), aD);                                        \
            gl_lds16(aSrc1 + (k0), aD + 2048);                                 \
            gl_lds16(gSrc + (k0),            bD);                              \
            gl_lds16(gSrc + 32 * DIM + (k0), bD + 2048);                       \
            gl_lds16(gSrc + 64 * DIM + (k0), bD + 4096);                       \
            gl_lds16(gSrc + 96 * DIM + (k0), bD + 6144);                       \
            gl_lds16(uSrc + (k0),            bD + 8192);                       \
            gl_lds16(uSrc + 32 * DIM + (k0), bD + 10240);                      \
            gl_lds16(uSrc + 64 * DIM + (k0), bD + 12288);                      \
            gl_lds16(uSrc + 96 * DIM + (k0), bD + 14336);                      \
        } while (0)

    P1_STAGE(0, 0);
    __syncthreads();

    int cur = 0;
    for (int k0 = 0; k0 < DIM; k0 += 64) {
        if (k0 + 64 < DIM) P1_STAGE(cur ^ 1, k0 + 64);
        const bf16* Ab = As + cur * 4096;
        const bf16* Bb = Bs + cur * 16384;
#pragma unroll
        for (int kh = 0; kh < 2; ++kh) {
            int cx = ((kh * 4 + quad) ^ mx7) * 8;
            bf16x8 a[4], bg[2], bu[2];
#pragma unroll
            for (int mg = 0; mg < 4; ++mg)
                a[mg] = *(const bf16x8*)(Ab + (mg * 16 + m) * 64 + cx);
#pragma unroll
            for (int j = 0; j < 2; ++j) {
                bg[j] = *(const bf16x8*)(Bb + (w * 32 + j * 16 + m) * 64 + cx);
                bu[j] = *(const bf16x8*)(Bb + (128 + w * 32 + j * 16 + m) * 64 + cx);
            }
#pragma unroll
            for (int j = 0; j < 2; ++j)
#pragma unroll
                for (int mg = 0; mg < 4; ++mg) {
                    aG[mg][j] = MFMA16(a[mg], bg[j], aG[mg][j]);
                    aU[mg][j] = MFMA16(a[mg], bu[j], aU[mg][j]);
                }
        }
        __syncthreads();
        cur ^= 1;
    }
    #undef P1_STAGE

#pragma unroll
    for (int mg = 0; mg < 4; ++mg)
#pragma unroll
        for (int j = 0; j < 2; ++j)
#pragma unroll
            for (int r4 = 0; r4 < 4; ++r4) {
                float gv = aG[mg][j][r4], uv = aU[mg][j][r4];
                float h = gv / (1.f + __expf(-gv)) * uv;
                hout[(size_t)(mg * 16 + quad * 4 + r4) * hstride + w * 32 + j * 16 + m] = (bf16)h;
            }
}

// ---------------------------------------------------------------- phase 2 (routed down; R4 config + XCD chunking)
__global__ __launch_bounds__(256, 4)
void phase2(const bf16* __restrict__ Hg, const bf16* __restrict__ wd,
            const int* __restrict__ counts, const float* __restrict__ slist,
            const int* __restrict__ items, const int* __restrict__ nitems,
            bf16* __restrict__ Od) {
    __shared__ __align__(16) bf16 As[2 * 64 * 32];
    __shared__ __align__(16) bf16 Bs[2 * 256 * 32];
    __shared__ float ssc[64];

    int rbk = xcd_swz(blockIdx.x, 544);
    if (rbk >= *nitems) return;
    int it = items[rbk];
    int e = it >> 24, t = (it >> 16) & 0xff, rowbase = it & 0xffff;
    int n0 = blockIdx.y * 256;
    int cnt = counts[e];

    int tid = threadIdx.x;
    if (tid < 64) {
        int li = t * 64 + tid;
        ssc[tid] = (li < cnt) ? slist[(size_t)e * N_TOK + li] : 0.f;
    }

    int r = tid >> 2;
    int chunk = (((tid & 3) ^ ((tid >> 3) & 3))) * 8;
    const bf16* aSrc = Hg + (size_t)(rowbase + r) * H_E + chunk;
    const bf16* bSrc = wd + (size_t)e * DIM * H_E + (size_t)(n0 + r) * H_E + chunk;

    int w = tid >> 6, lane = tid & 63, m = lane & 15, quad = lane >> 4;
    int quadx = quad ^ ((m >> 1) & 3);
    floatx4 acc[4][4] = {{{0}}};

    #define P2_STAGE(buf, k0)                                                  \
        do {                                                                   \
            bf16* aD = As + (buf) * 2048 + tid * 8;                            \
            bf16* bD = Bs + (buf) * 8192 + tid * 8;                            \
            gl_lds16(aSrc + (k0), aD);                                         \
            _Pragma("unroll")                                                  \
            for (int p = 0; p < 4; ++p)                                        \
                gl_lds16(bSrc + (size_t)p * 64 * H_E + (k0), bD + p * 2048);   \
        } while (0)

    P2_STAGE(0, 0);
    __syncthreads();

    int cur = 0;
    for (int k0 = 0; k0 < H_E; k0 += 32) {
        if (k0 + 32 < H_E) P2_STAGE(cur ^ 1, k0 + 32);
        const bf16* Ab = As + cur * 2048;
        const bf16* Bb = Bs + cur * 8192;
        bf16x8 a[4], bb[4];
#pragma unroll
        for (int mg = 0; mg < 4; ++mg)
            a[mg] = *(const bf16x8*)(Ab + (mg * 16 + m) * 32 + quadx * 8);
#pragma unroll
        for (int ng = 0; ng < 4; ++ng)
            bb[ng] = *(const bf16x8*)(Bb + (w * 64 + ng * 16 + m) * 32 + quadx * 8);
#pragma unroll
        for (int ng = 0; ng < 4; ++ng)
#pragma unroll
            for (int mg = 0; mg < 4; ++mg)
                acc[mg][ng] = MFMA16(a[mg], bb[ng], acc[mg][ng]);
        __syncthreads();
        cur ^= 1;
    }
    #undef P2_STAGE

#pragma unroll
    for (int mg = 0; mg < 4; ++mg)
#pragma unroll
        for (int r4 = 0; r4 < 4; ++r4) {
            int row = mg * 16 + quad * 4 + r4;
            float sc = ssc[row];
            bf16* op = Od + (size_t)(rowbase + row) * DIM + n0 + w * 64 + m;
#pragma unroll
            for (int ng = 0; ng < 4; ++ng)
                op[ng * 16] = (bf16)(acc[mg][ng][r4] * sc);
        }
}

// ---------------------------------------------------------------- shared down + routed reduce (R4 config + XCD chunking)
__global__ __launch_bounds__(256, 4)
void shared_down(const bf16* __restrict__ Hs, const bf16* __restrict__ sd,
                 const bf16* __restrict__ Od, const int* __restrict__ tok2slot,
                 const int* __restrict__ expbase, float* __restrict__ out) {
    __shared__ __align__(16) bf16 As[2 * 64 * 32];
    __shared__ __align__(16) bf16 Bs[2 * 256 * 32];
    __shared__ int srow[64][4];

    int t0 = xcd_swz(blockIdx.x, 128) * 64;
    int n0 = blockIdx.y * 256;
    int tid = threadIdx.x;

    if (tid < 64) {
        const int* t2s = tok2slot + (size_t)(t0 + tid) * 4;
#pragma unroll
        for (int k = 0; k < 4; ++k) {
            int v = t2s[k];
            srow[tid][k] = expbase[v >> 16] + (v & 0xffff);
        }
    }

    int r = tid >> 2;
    int chunk = (((tid & 3) ^ ((tid >> 3) & 3))) * 8;
    const bf16* aSrc = Hs + (size_t)(t0 + r) * HS + chunk;
    const bf16* bSrc = sd + (size_t)(n0 + r) * HS + chunk;

    int w = tid >> 6, lane = tid & 63, m = lane & 15, quad = lane >> 4;
    int quadx = quad ^ ((m >> 1) & 3);
    floatx4 acc[4][4] = {{{0}}};

    #define SD_STAGE(buf, k0)                                                  \
        do {                                                                   \
            bf16* aD = As + (buf) * 2048 + tid * 8;                            \
            bf16* bD = Bs + (buf) * 8192 + tid * 8;                            \
            gl_lds16(aSrc + (k0), aD);                                         \
            _Pragma("unroll")                                                  \
            for (int p = 0; p < 4; ++p)                                        \
                gl_lds16(bSrc + (size_t)p * 64 * HS + (k0), bD + p * 2048);    \
        } while (0)

    SD_STAGE(0, 0);
    __syncthreads();

    int cur = 0;
    for (int tt = 0; tt < 16; ++tt) {
        if (tt < 15) SD_STAGE(cur ^ 1, (tt + 1) * 32);
        const bf16* Ab = As + cur * 2048;
        const bf16* Bb = Bs + cur * 8192;
        bf16x8 a[4], bb[4];
#pragma unroll
        for (int mg = 0; mg < 4; ++mg)
            a[mg] = *(const bf16x8*)(Ab + (mg * 16 + m) * 32 + quadx * 8);
#pragma unroll
        for (int ng = 0; ng < 4; ++ng)
            bb[ng] = *(const bf16x8*)(Bb + (w * 64 + ng * 16 + m) * 32 + quadx * 8);
#pragma unroll
        for (int ng = 0; ng < 4; ++ng)
#pragma unroll
            for (int mg = 0; mg < 4; ++mg)
                acc[mg][ng] = MFMA16(a[mg], bb[ng], acc[mg][ng]);
        __syncthreads();
        cur ^= 1;
    }
    #undef SD_STAGE

#pragma unroll
    for (int mg = 0; mg < 4; ++mg)
#pragma unroll
        for (int r4 = 0; r4 < 4; ++r4) {
            int rl = mg * 16 + quad * 4 + r4;
            size_t r0 = (size_t)srow[rl][0] * DIM;
            size_t r1 = (size_t)srow[rl][1] * DIM;
            size_t r2 = (size_t)srow[rl][2] * DIM;
            size_t r3 = (size_t)srow[rl][3] * DIM;
            float* op = out + (size_t)(t0 + rl) * DIM + n0 + w * 64 + m;
#pragma unroll
            for (int ng = 0; ng < 4; ++ng) {
                int col = n0 + w * 64 + ng * 16 + m;
                float v = acc[mg][ng][r4]
                        + (float)Od[r0 + col] + (float)Od[r1 + col]
                        + (float)Od[r2 + col] + (float)Od[r3 + col];
                op[ng * 16] = v;
            }
        }
}

// ---------------------------------------------------------------- launch
extern "C" void kernel_launch(void* const* d_in, const int* in_sizes, int n_in,
                              void* d_out, int out_size, void* d_ws, size_t ws_size,
                              hipStream_t stream) {
    (void)in_sizes; (void)n_in; (void)out_size; (void)ws_size;
    const float* x   = (const float*)d_in[0];
    const float* rw  = (const float*)d_in[1];
    const float* rb  = (const float*)d_in[2];
    const float* gw  = (const float*)d_in[3];
    const float* uw  = (const float*)d_in[4];
    const float* dw  = (const float*)d_in[5];
    const float* sgw = (const float*)d_in[6];
    const float* suw = (const float*)d_in[7];
    const float* sdw = (const float*)d_in[8];
    float* out = (float*)d_out;

    char* ws = (char*)d_ws;
    size_t o = 0;
    bf16* xb  = (bf16*)(ws + o); o += (size_t)N_TOK * DIM * 2;
    bf16* wgb = (bf16*)(ws + o); o += (size_t)E_R * H_E * DIM * 2;
    bf16* wub = (bf16*)(ws + o); o += (size_t)E_R * H_E * DIM * 2;
    bf16* wdb = (bf16*)(ws + o); o += (size_t)E_R * DIM * H_E * 2;
    bf16* sgb = (bf16*)(ws + o); o += (size_t)HS * DIM * 2;
    bf16* sub = (bf16*)(ws + o); o += (size_t)HS * DIM * 2;
    bf16* sdb = (bf16*)(ws + o); o += (size_t)DIM * HS * 2;
    bf16* Hg  = (bf16*)(ws + o); o += (size_t)MAXSLOT * H_E * 2;
    bf16* Hs  = (bf16*)(ws + o); o += (size_t)N_TOK * HS * 2;
    bf16* Od  = (bf16*)(ws + o); o += (size_t)MAXSLOT * DIM * 2;
    float* partial = (float*)(ws + o); o += (size_t)RKS * N_TOK * 32 * 4;
    int*   counts = (int*)(ws + o);   o += 256;
    int*   tlist  = (int*)(ws + o);   o += (size_t)E_R * N_TOK * 4;
    float* slist  = (float*)(ws + o); o += (size_t)E_R * N_TOK * 4;
    int*   tok2slot = (int*)(ws + o); o += (size_t)N_TOK * 4 * 4;
    int*   items  = (int*)(ws + o);   o += 4096;
    int*   nitems = (int*)(ws + o);   o += 64;
    int*   expbase = (int*)(ws + o);  o += 256;

    hipMemsetAsync(counts, 0, E_R * sizeof(int), stream);

    router_gemm<<<dim3(N_TOK / 64, RKS), 256, 0, stream>>>(x, rw, partial, xb);
    router_fin<<<N_TOK / 256, 256, 0, stream>>>(partial, rb, counts, tlist, slist,
                                                tok2slot);
    cvt_all<<<6912, 256, 0, stream>>>(gw, uw, dw, sgw, suw, sdw,
                                      wgb, wub, wdb, sgb, sub, sdb);
    wq_build<<<1, 64, 0, stream>>>(counts, items, nitems, expbase);
    phase1<<<1056, 256, 0, stream>>>(xb, wgb, wub, sgb, sub, counts, tlist,
                                     items, nitems, Hg, Hs);
    phase2<<<dim3(544, 4), 256, 0, stream>>>(Hg, wdb, counts, slist,
                                             items, nitems, Od);
    shared_down<<<dim3(N_TOK / 64, 4), 256, 0, stream>>>(Hs, sdb, Od, tok2slot,
                                                         expbase, out);
}